// Round 4
// baseline (69.976 us; speedup 1.0000x reference)
//
#include <hip/hip_runtime.h>

// GraphAttentionLayer collapses algebraically:
//   a[i,j] = s[i] (constant over j) => softmax row = uniform 1/N
//   out[i] = mean_j h[j] = (mean_j x[j]) @ W.T + b   (identical for every row i)
// Structure: one tiny memset node (zeroes fixed-point accumulators + barrier
// counter) + ONE fused kernel with a hand-rolled spin barrier (plain launch;
// cooperative launch measured 2.3x worse, 3 kernel nodes measured 23.8us,
// 2 nodes 20.35us -> node count is the lever).
// Determinism: cross-block accumulation uses int64 fixed-point atomicAdd
// (associative+commutative => order-independent, bitwise identical replays).

#define N_ROWS 8192
#define F_IN   256
#define F_OUT  128
#define NBLK   256
#define RPB    (N_ROWS / NBLK)        // 32 rows per block
#define FP_SCALE 4294967296.0         // 2^32

__global__ void __launch_bounds__(256, 1)
gat_fused(const float* __restrict__ x, const float* __restrict__ W,
          const float* __restrict__ b,
          unsigned long long* __restrict__ xsumI,  // [F_IN] fixed-point col sums
          unsigned int* __restrict__ ctr,          // barrier counter (memset to 0)
          float* __restrict__ out)
{
    __shared__ float  Wl[F_OUT][F_IN + 1];   // +1 pad: conflict-free Wl[t][k]
    __shared__ double xbar[F_IN];
    __shared__ float  mrow[F_OUT];
    const int t = threadIdx.x, blk = blockIdx.x;

    // ---- Phase 1: 32-row partial column sum, fixed-point atomic accumulate ----
    {
        const float* xp = x + (size_t)blk * RPB * F_IN + t;
        float s = 0.f;
#pragma unroll
        for (int r = 0; r < RPB; ++r)
            s += xp[r * F_IN];
        long long q = (long long)rint((double)s * FP_SCALE);
        atomicAdd(&xsumI[t], (unsigned long long)q);   // device scope, exact int add
    }

    // ---- Stage W into LDS (coalesced float4) BEFORE the barrier: overlaps spin ----
    {
        const float4* W4 = (const float4*)W;           // 8192 float4
#pragma unroll
        for (int j = 0; j < (F_OUT * F_IN / 4) / 256; ++j) {   // 32 iters
            float4 v = W4[j * 256 + t];
            int idx = (j * 256 + t) * 4;
            int f = idx >> 8, k = idx & 255;
            Wl[f][k] = v.x; Wl[f][k + 1] = v.y; Wl[f][k + 2] = v.z; Wl[f][k + 3] = v.w;
        }
    }

    // ---- Spin barrier: all xsumI adds globally visible, then everyone passes ----
    __threadfence();          // order my atomics before my arrival
    __syncthreads();          // whole block's atomics issued+fenced
    if (t == 0) {
        __hip_atomic_fetch_add(ctr, 1u, __ATOMIC_ACQ_REL, __HIP_MEMORY_SCOPE_AGENT);
        while (__hip_atomic_load(ctr, __ATOMIC_RELAXED, __HIP_MEMORY_SCOPE_AGENT) < NBLK)
            __builtin_amdgcn_s_sleep(8);
    }
    __syncthreads();
    __threadfence();          // acquire side

    // ---- Phase 2: read exact integer column sums -> xbar; matvec -> mrow ----
    {
        unsigned long long v =
            __hip_atomic_load(&xsumI[t], __ATOMIC_RELAXED, __HIP_MEMORY_SCOPE_AGENT);
        xbar[t] = (double)(long long)v * (1.0 / (FP_SCALE * (double)N_ROWS));
    }
    __syncthreads();
    if (t < F_OUT) {
        double c0 = 0.0, c1 = 0.0, c2 = 0.0, c3 = 0.0;
#pragma unroll 8
        for (int k = 0; k < F_IN; k += 4) {
            c0 += xbar[k + 0] * (double)Wl[t][k + 0];
            c1 += xbar[k + 1] * (double)Wl[t][k + 1];
            c2 += xbar[k + 2] * (double)Wl[t][k + 2];
            c3 += xbar[k + 3] * (double)Wl[t][k + 3];
        }
        mrow[t] = (float)(((c0 + c1) + (c2 + c3)) + (double)b[t]);
    }
    __syncthreads();

    // ---- Phase 3: broadcast mrow into this block's 32 output rows ----
    // 32 rows * 128 f32 = 1024 float4; 4 stores/thread, fully coalesced.
    const float4 v = ((const float4*)mrow)[t & (F_OUT / 4 - 1)];  // (t+j*256)&31 == t&31
    float4* o4 = (float4*)out + (size_t)blk * (RPB * F_OUT / 4);
#pragma unroll
    for (int j = 0; j < 4; ++j)
        o4[t + j * 256] = v;
}

extern "C" void kernel_launch(void* const* d_in, const int* in_sizes, int n_in,
                              void* d_out, int out_size, void* d_ws, size_t ws_size,
                              hipStream_t stream) {
    const float* x = (const float*)d_in[0];   // [8192, 256]
    // d_in[1] = adj (unused)
    const float* W = (const float*)d_in[2];   // [128, 256]
    const float* b = (const float*)d_in[3];   // [128]
    // d_in[4] = Wa, d_in[5] = ba (algebraically dead)
    float* out = (float*)d_out;               // [8192, 128]

    unsigned long long* xsumI = (unsigned long long*)d_ws;          // 2048 B
    unsigned int*       ctr   = (unsigned int*)((char*)d_ws + 2048);

    // Zero accumulators + barrier counter (graph-capturable async memset node).
    hipMemsetAsync(d_ws, 0, 2048 + 64, stream);

    gat_fused<<<NBLK, 256, 0, stream>>>(x, W, b, xsumI, ctr, out);
}

// Round 6
// 58.346 us; speedup vs baseline: 1.1993x; 1.1993x over previous
//
#include <hip/hip_runtime.h>

// GraphAttentionLayer collapses algebraically:
//   a[i,j] = s[i] (constant over j) => softmax row = uniform 1/N
//   out[i] = mean_j h[j] = (mean_j x[j]) @ W.T + b   (identical for every row i)
//
// ONE plain kernel node (measured: 3 nodes=23.8us, 2 nodes=20.35us, coop=54.7us,
// memset+atomic-spin=70us -> node count is the lever, atomics/memset are poison).
// Cross-block handoff: plain stores of part[] + per-block MAGIC flag stores
// (no init needed: stores overwrite poison; no contended atomics). Stale-MAGIC
// flags from a previous replay are benign because part[] is a pure function of
// x and bitwise identical every replay -> any old/new mix is the correct value.

#define N_ROWS 8192
#define F_IN   256
#define F_OUT  128
#define NBLK   256
#define RPB    (N_ROWS / NBLK)   // 32 rows per block
#define MAGIC  0x5A5A1234u

__global__ void __launch_bounds__(256)
gat_onekernel(const float* __restrict__ x, const float* __restrict__ W,
              const float* __restrict__ b, float* __restrict__ part,
              unsigned int* __restrict__ done, float* __restrict__ out)
{
    const int t = threadIdx.x, blk = blockIdx.x;

    // ---- Phase 1: colsum of this block's 32 rows -> part[blk][t] (coalesced) ----
    {
        const float* xp = x + (size_t)blk * RPB * F_IN + t;
        float s = 0.f;
#pragma unroll
        for (int r = 0; r < RPB; ++r)
            s += xp[r * F_IN];
        part[blk * F_IN + t] = s;
    }

    // ---- Release part writes, then publish this block's flag (plain store) ----
    __threadfence();
    __syncthreads();
    if (t == 0)
        __hip_atomic_store(&done[blk], MAGIC, __ATOMIC_RELEASE,
                           __HIP_MEMORY_SCOPE_AGENT);

    // ---- Barrier: thread t polls flag t; all 256 flags MAGIC => all parts ok ----
    while (__hip_atomic_load(&done[t], __ATOMIC_RELAXED,
                             __HIP_MEMORY_SCOPE_AGENT) != MAGIC)
        __builtin_amdgcn_s_sleep(2);
    __syncthreads();
    __threadfence();   // acquire side: order flag observation before part reads

    // ---- Phase 2: redundant deterministic reduce + matvec (identical per block) ----
    __shared__ double xbar[F_IN];
    __shared__ double psum[256];
    __shared__ float  mrow[F_OUT];
    {
        double a0 = 0, a1 = 0, a2 = 0, a3 = 0;
#pragma unroll 4
        for (int p = 0; p < NBLK; p += 4) {       // coalesced column reads, L2-hot
            a0 += (double)part[(p + 0) * F_IN + t];
            a1 += (double)part[(p + 1) * F_IN + t];
            a2 += (double)part[(p + 2) * F_IN + t];
            a3 += (double)part[(p + 3) * F_IN + t];
        }
        xbar[t] = ((a0 + a1) + (a2 + a3)) * (1.0 / (double)N_ROWS);
    }
    __syncthreads();
    {
        // thread t computes half of mrow[f]: f = t/2, k-range [kb, kb+128)
        const int f = t >> 1, kb = (t & 1) * (F_IN / 2);
        const float* wr = W + (size_t)f * F_IN + kb;   // L2/L3-resident (128 KB)
        double c0 = 0, c1 = 0, c2 = 0, c3 = 0;
#pragma unroll 8
        for (int k = 0; k < F_IN / 2; k += 4) {
            c0 += xbar[kb + k + 0] * (double)wr[k + 0];
            c1 += xbar[kb + k + 1] * (double)wr[k + 1];
            c2 += xbar[kb + k + 2] * (double)wr[k + 2];
            c3 += xbar[kb + k + 3] * (double)wr[k + 3];
        }
        psum[t] = (c0 + c1) + (c2 + c3);
    }
    __syncthreads();
    if (t < F_OUT)
        mrow[t] = (float)((psum[2 * t] + psum[2 * t + 1]) + (double)b[t]);
    __syncthreads();

    // ---- Phase 3: write this block's 32 output rows (1024 float4, coalesced) ----
    const float4 v = ((const float4*)mrow)[t & (F_OUT / 4 - 1)]; // (t+j*256)&31 == t&31
    float4* o4 = (float4*)out + (size_t)blk * (RPB * F_OUT / 4);
#pragma unroll
    for (int j = 0; j < 4; ++j)
        o4[t + j * 256] = v;
}

extern "C" void kernel_launch(void* const* d_in, const int* in_sizes, int n_in,
                              void* d_out, int out_size, void* d_ws, size_t ws_size,
                              hipStream_t stream) {
    const float* x = (const float*)d_in[0];   // [8192, 256]
    // d_in[1] = adj (unused)
    const float* W = (const float*)d_in[2];   // [128, 256]
    const float* b = (const float*)d_in[3];   // [128]
    // d_in[4] = Wa, d_in[5] = ba (algebraically dead)
    float* out = (float*)d_out;               // [8192, 128]

    float*        part = (float*)d_ws;                          // 256*256*4 = 256 KB
    unsigned int* done = (unsigned int*)((char*)d_ws + NBLK * F_IN * sizeof(float));

    gat_onekernel<<<NBLK, 256, 0, stream>>>(x, W, b, part, done, out);
}

// Round 7
// 16.621 us; speedup vs baseline: 4.2101x; 3.5103x over previous
//
#include <hip/hip_runtime.h>

// GraphAttentionLayer collapses algebraically:
//   a[i,j] = s[i] (constant over j) => softmax row = uniform 1/N
//   out[i] = mean_j h[j] = (mean_j x[j]) @ W.T + b   (identical for every row i)
//
// Shape: TWO plain kernel nodes. Measured: 3 nodes=23.8us, 2 nodes=20.35us,
// 1-node variants with in-kernel sync = 54.7/70/58.3us (agent-scope fences
// force per-XCD L2 writeback/invalidate + fabric-flooding spins -> the kernel
// boundary IS the cheapest global barrier). This round: shave kernel work
// (smaller part array, no redundant W in the reduce path, deeper ILP).

#define N_ROWS 8192
#define F_IN   256
#define F_OUT  128
#define NB1    128
#define T1     512
#define RPB1   (N_ROWS / NB1)        // 64 rows per K1 block
#define NB2    128
#define T2     1024
#define RPB2   (N_ROWS / NB2)        // 64 out rows per K2 block

// K1: partial column sums. part[p][c] f32, p<128, c<256 (128 KB).
__global__ void __launch_bounds__(T1)
gat_colsum(const float* __restrict__ x, float* __restrict__ part) {
    __shared__ float cs2[2][F_IN];
    const int t = threadIdx.x, blk = blockIdx.x;
    const int col = t & (F_IN - 1), grp = t >> 8;          // grp in {0,1}
    const float* xp = x + ((size_t)blk * RPB1 + grp * 32) * F_IN + col;
    float s = 0.f;
#pragma unroll
    for (int r = 0; r < 32; ++r)
        s += xp[(size_t)r * F_IN];                         // coalesced (1KB/row)
    cs2[grp][col] = s;
    __syncthreads();
    if (t < F_IN)
        part[blk * F_IN + t] = cs2[0][t] + cs2[1][t];      // fixed order, f32
}

// K2: redundant deterministic reduce + matvec + broadcast (per-block identical).
__global__ void __launch_bounds__(T2, 1)
gat_finish(const float* __restrict__ part, const float* __restrict__ W,
           const float* __restrict__ b, float* __restrict__ out) {
    __shared__ float  Wl[F_OUT][F_IN + 1];   // 131.6 KB, +1 pad
    __shared__ double red[T2];               // reused: phase-A csp, phase-C psum
    __shared__ double cs_d[F_IN];
    __shared__ float  mrow[F_OUT];
    const int t = threadIdx.x;

    // Stage W -> LDS: 8192 float4 over 1024 threads = 8 coalesced iters.
    const float4* W4 = (const float4*)W;
#pragma unroll
    for (int j = 0; j < 8; ++j) {
        float4 v = W4[j * T2 + t];
        int idx = (j * T2 + t) * 4, f = idx >> 8, k = idx & 255;
        Wl[f][k] = v.x; Wl[f][k + 1] = v.y; Wl[f][k + 2] = v.z; Wl[f][k + 3] = v.w;
    }

    // Phase A: column-reduce part. f = t&255, h = t>>8 in {0..3}, 32 p's each,
    // 4-way ILP -> 8 dependent rounds of IC-latency. Coalesced across f.
    {
        const int f = t & (F_IN - 1), ps = (t >> 8) * 32;
        double a0 = 0, a1 = 0, a2 = 0, a3 = 0;
#pragma unroll 2
        for (int i = 0; i < 32; i += 4) {
            a0 += (double)part[(ps + i + 0) * F_IN + f];
            a1 += (double)part[(ps + i + 1) * F_IN + f];
            a2 += (double)part[(ps + i + 2) * F_IN + f];
            a3 += (double)part[(ps + i + 3) * F_IN + f];
        }
        red[t] = (a0 + a1) + (a2 + a3);
    }
    __syncthreads();
    if (t < F_IN)
        cs_d[t] = ((red[t] + red[t + 256]) + (red[t + 512] + red[t + 768]))
                  * (1.0 / (double)N_ROWS);
    __syncthreads();   // also guards red[] reuse below

    // Phase C: matvec mrow[f] = dot(Wl[f], cs_d). f = t&127, oct = t>>7,
    // kb = oct*32 -> 32 MACs/thread from LDS. Wave has fixed oct, f spans 64
    // -> Wl banks 2-way (free); cs_d[k] is broadcast (free).
    {
        const int f = t & (F_OUT - 1), kb = (t >> 7) * 32;
        double c0 = 0, c1 = 0, c2 = 0, c3 = 0;
#pragma unroll 2
        for (int k = 0; k < 32; k += 4) {
            c0 += cs_d[kb + k + 0] * (double)Wl[f][kb + k + 0];
            c1 += cs_d[kb + k + 1] * (double)Wl[f][kb + k + 1];
            c2 += cs_d[kb + k + 2] * (double)Wl[f][kb + k + 2];
            c3 += cs_d[kb + k + 3] * (double)Wl[f][kb + k + 3];
        }
        red[t] = (c0 + c1) + (c2 + c3);
    }
    __syncthreads();
    if (t < F_OUT) {
        double m = ((red[t] + red[t + 128]) + (red[t + 256] + red[t + 384]))
                 + ((red[t + 512] + red[t + 640]) + (red[t + 768] + red[t + 896]));
        mrow[t] = (float)(m + (double)b[t]);
    }
    __syncthreads();

    // Broadcast: 64 rows x 128 f32 = 2048 float4; 1024 threads -> 2 stores each.
    const float4 v = ((const float4*)mrow)[t & (F_OUT / 4 - 1)];  // (t+j*1024)&31==t&31
    float4* o4 = (float4*)out + (size_t)blockIdx.x * (RPB2 * F_OUT / 4);
    o4[t] = v;
    o4[t + T2] = v;
}

extern "C" void kernel_launch(void* const* d_in, const int* in_sizes, int n_in,
                              void* d_out, int out_size, void* d_ws, size_t ws_size,
                              hipStream_t stream) {
    const float* x = (const float*)d_in[0];   // [8192, 256]
    // d_in[1] = adj (unused)
    const float* W = (const float*)d_in[2];   // [128, 256]
    const float* b = (const float*)d_in[3];   // [128]
    // d_in[4] = Wa, d_in[5] = ba (algebraically dead)
    float* out  = (float*)d_out;              // [8192, 128]
    float* part = (float*)d_ws;               // NB1*F_IN f32 = 128 KB

    gat_colsum<<<NB1, T1, 0, stream>>>(x, part);
    gat_finish<<<NB2, T2, 0, stream>>>(part, W, b, out);
}